// Round 5
// baseline (392.418 us; speedup 1.0000x reference)
//
#include <hip/hip_runtime.h>
#include <math.h>

#define N_NODES 100000
#define N_EDGES 600000
#define N_GRAPHS 512
#define D 128
#define SCAN_BS 1024
#define SCAN_NBC ((N_NODES + SCAN_BS - 1) / SCAN_BS)   // 98
#define NPART 8
#define PART_SZ (N_NODES / NPART)                      // 12500
#define E4 (N_EDGES / 4)                               // 150000
#define SPLIT_B 12500                                  // (N*D/4)/256

typedef unsigned short u16;
typedef __attribute__((ext_vector_type(8))) short short8;
typedef __attribute__((ext_vector_type(4))) float f32x4;

__device__ __forceinline__ u16 f2bf(float f) {
    unsigned int u = __float_as_uint(f);
    u += 0x7FFFu + ((u >> 16) & 1u);
    return (u16)(u >> 16);
}
__device__ __forceinline__ float bf2f(u16 h) {
    return __uint_as_float(((unsigned int)h) << 16);
}
// fp32 -> (hi bf16 bits, lo bf16 bits) in low 16 of each
__device__ __forceinline__ void split2(float f, unsigned int& h16, unsigned int& l16) {
    unsigned int u = __float_as_uint(f);
    unsigned int hb = (u + (0x7FFFu + ((u >> 16) & 1u))) & 0xffff0000u;
    float lo = f - __uint_as_float(hb);
    unsigned int ul = __float_as_uint(lo);
    h16 = hb >> 16;
    l16 = (ul + (0x7FFFu + ((ul >> 16) & 1u))) >> 16;
}

// async global->LDS, 16 B per lane. LDS dest must be wave-uniform base + lane*16.
typedef __attribute__((address_space(1))) const unsigned int gas_u32;
typedef __attribute__((address_space(3))) unsigned int las_u32;
__device__ __forceinline__ void gload16(const void* g, void* l) {
    __builtin_amdgcn_global_load_lds((gas_u32*)g, (las_u32*)l, 16, 0, 0);
}

// ---------------- zero helper ----------------
__global__ __launch_bounds__(256) void zero_i_kernel(int* __restrict__ p, int n) {
    int i = blockIdx.x * 256 + threadIdx.x;
    if (i < n) p[i] = 0;
}

// ---------------- CSR build ----------------
// hist: plain unpartitioned (atomics execute at the device coherence point, so
// XCD-partitioning bought nothing -- R3 post-mortem). fill: KEEPS dst-range
// partitioning: its win is the csr_src SCATTER-STORE locality in the owning
// XCD's L2 (R2: 41.8us/40.6MB writes -> R3: out of top-5).
__global__ __launch_bounds__(256) void hist_kernel(const int* __restrict__ dst,
                                                   int* __restrict__ deg) {
    int e = blockIdx.x * 256 + threadIdx.x;
    if (e < N_EDGES) atomicAdd(&deg[dst[e]], 1);
}

__global__ __launch_bounds__(1024) void scan1_kernel(const int* __restrict__ deg,
                                                     int* __restrict__ excl,
                                                     int* __restrict__ blocksum) {
    __shared__ int buf[2][SCAN_BS];
    const int t = threadIdx.x;
    const int gid = blockIdx.x * SCAN_BS + t;
    int v = (gid < N_NODES) ? deg[gid] : 0;
    buf[0][t] = v;
    __syncthreads();
    int pi = 0;
    for (int off = 1; off < SCAN_BS; off <<= 1) {
        int val = buf[pi][t];
        if (t >= off) val += buf[pi][t - off];
        buf[pi ^ 1][t] = val;
        pi ^= 1;
        __syncthreads();
    }
    int incl = buf[pi][t];
    if (gid < N_NODES) excl[gid] = incl - v;
    if (t == SCAN_BS - 1) blocksum[blockIdx.x] = incl;
}

// scan3 with the block-total prefix computed locally (merged scan2)
__global__ __launch_bounds__(256) void scan3_kernel(const int* __restrict__ excl,
                                                    const int* __restrict__ blocksum,
                                                    int* __restrict__ rowptr) {
    __shared__ int buf[2][128];
    const int t = threadIdx.x;
    if (t < 128) buf[0][t] = (t < SCAN_NBC) ? blocksum[t] : 0;
    __syncthreads();
    int pi = 0;
    for (int off = 1; off < 128; off <<= 1) {
        if (t < 128) {
            int val = buf[pi][t];
            if (t >= off) val += buf[pi][t - off];
            buf[pi ^ 1][t] = val;
        }
        pi ^= 1;
        __syncthreads();
    }
    const int i = blockIdx.x * 256 + t;
    if (i < N_NODES) {
        const int j = i / SCAN_BS;
        const int pref = (j == 0) ? 0 : buf[pi][j - 1];
        rowptr[i] = excl[i] + pref;
    }
    if (i == 0) rowptr[N_NODES] = N_EDGES;
}

__global__ __launch_bounds__(256) void fill_kernel(const int* __restrict__ src,
                                                   const int* __restrict__ dst,
                                                   const int* __restrict__ rowptr,
                                                   int* __restrict__ fill,
                                                   int* __restrict__ csr_src) {
    const int lo = (blockIdx.x & (NPART - 1)) * PART_SZ;
    const int i4 = (blockIdx.x >> 3) * 256 + threadIdx.x;
    if (i4 >= E4) return;
    const int4 d4 = ((const int4*)dst)[i4];
    const int4 s4 = ((const int4*)src)[i4];
    if ((unsigned)(d4.x - lo) < (unsigned)PART_SZ) {
        int pos = rowptr[d4.x] + atomicAdd(&fill[d4.x], 1);
        csr_src[pos] = s4.x;
    }
    if ((unsigned)(d4.y - lo) < (unsigned)PART_SZ) {
        int pos = rowptr[d4.y] + atomicAdd(&fill[d4.y], 1);
        csr_src[pos] = s4.y;
    }
    if ((unsigned)(d4.z - lo) < (unsigned)PART_SZ) {
        int pos = rowptr[d4.z] + atomicAdd(&fill[d4.z], 1);
        csr_src[pos] = s4.z;
    }
    if ((unsigned)(d4.w - lo) < (unsigned)PART_SZ) {
        int pos = rowptr[d4.w] + atomicAdd(&fill[d4.w], 1);
        csr_src[pos] = s4.w;
    }
}

// ---------------- fused prep: split x into bf16 hi/lo planes + pack W ----------------
__global__ __launch_bounds__(256) void prep_kernel(const float* __restrict__ x,
                                                   u16* __restrict__ Hhi,
                                                   u16* __restrict__ Hlo,
                                                   const float* __restrict__ Wl1, const float* __restrict__ Wr1,
                                                   const float* __restrict__ Wl2, const float* __restrict__ Wr2,
                                                   const float* __restrict__ Wl3, const float* __restrict__ Wr3,
                                                   u16* __restrict__ wph, u16* __restrict__ wpl) {
    if (blockIdx.x < SPLIT_B) {
        const int i = blockIdx.x * 256 + threadIdx.x;   // 4 elems/thread
        const float4 v = ((const float4*)x)[i];
        unsigned int h0, l0, h1, l1, h2, l2, h3, l3;
        split2(v.x, h0, l0); split2(v.y, h1, l1);
        split2(v.z, h2, l2); split2(v.w, h3, l3);
        uint2 oh, ol;
        oh.x = h0 | (h1 << 16); oh.y = h2 | (h3 << 16);
        ol.x = l0 | (l1 << 16); ol.y = l2 | (l3 << 16);
        ((uint2*)Hhi)[i] = oh;
        ((uint2*)Hlo)[i] = ol;
    } else {
        const int b = (blockIdx.x - SPLIT_B) * 4 + (threadIdx.x >> 6);  // 0..191
        const int lane = threadIdx.x & 63;
        const int layer = b >> 6;
        const int t = b & 63;
        const float* Wl = (layer == 0) ? Wl1 : (layer == 1) ? Wl2 : Wl3;
        const float* Wr = (layer == 0) ? Wr1 : (layer == 1) ? Wr2 : Wr3;
        const int nt = t >> 3, kt = t & 7;
        const int n = nt * 16 + (lane & 15);
        const int k0 = kt * 32 + (lane >> 4) * 8;
        const size_t base = (size_t)layer * 32768 + (size_t)(t * 64 + lane) * 8;
        #pragma unroll
        for (int j = 0; j < 8; ++j) {
            const int k = k0 + j;
            const float w = (k < 128) ? Wl[k * 128 + n] : Wr[(k - 128) * 128 + n];
            const u16 h = f2bf(w);
            wph[base + j] = h;
            wpl[base + j] = f2bf(w - bf2f(h));
        }
    }
}

// ---------------- aggregation: mean of neighbor hi-plane rows -> bf16 Mb ----------------
// one wave per node, TWO neighbors in flight per wave-instruction (uint2/lane).
__global__ __launch_bounds__(256) void agg_kernel(const u16* __restrict__ Hhi,
                                                  const int* __restrict__ rowptr,
                                                  const int* __restrict__ csr_src,
                                                  u16* __restrict__ Mb) {
    const int lane = threadIdx.x & 63;
    const int half = lane >> 5;          // 0: even neighbor, 1: odd neighbor
    const int q = lane & 31;             // uint2 index within row (4 cols)
    const int node = blockIdx.x * 4 + (threadIdx.x >> 6);
    if (node >= N_NODES) return;
    const int beg = rowptr[node];
    const int end = rowptr[node + 1];
    const uint2* H64 = (const uint2*)Hhi;   // row stride 32 uint2
    float a0 = 0.f, a1 = 0.f, a2 = 0.f, a3 = 0.f;

    for (int c0 = beg; c0 < end; c0 += 64) {
        const int nv = min(64, end - c0);
        int msrc = (c0 + lane < end) ? csr_src[c0 + lane] : 0;
        int j = 0;
        for (; j + 8 <= nv; j += 8) {
            const int t0 = __shfl(msrc, j + 0 + half);
            const int t1 = __shfl(msrc, j + 2 + half);
            const int t2 = __shfl(msrc, j + 4 + half);
            const int t3 = __shfl(msrc, j + 6 + half);
            const uint2 w0 = H64[(size_t)t0 * 32 + q];
            const uint2 w1 = H64[(size_t)t1 * 32 + q];
            const uint2 w2 = H64[(size_t)t2 * 32 + q];
            const uint2 w3 = H64[(size_t)t3 * 32 + q];
            a0 += __uint_as_float(w0.x << 16) + __uint_as_float(w1.x << 16)
                + __uint_as_float(w2.x << 16) + __uint_as_float(w3.x << 16);
            a1 += __uint_as_float(w0.x & 0xffff0000u) + __uint_as_float(w1.x & 0xffff0000u)
                + __uint_as_float(w2.x & 0xffff0000u) + __uint_as_float(w3.x & 0xffff0000u);
            a2 += __uint_as_float(w0.y << 16) + __uint_as_float(w1.y << 16)
                + __uint_as_float(w2.y << 16) + __uint_as_float(w3.y << 16);
            a3 += __uint_as_float(w0.y & 0xffff0000u) + __uint_as_float(w1.y & 0xffff0000u)
                + __uint_as_float(w2.y & 0xffff0000u) + __uint_as_float(w3.y & 0xffff0000u);
        }
        for (; j + 2 <= nv; j += 2) {
            const int s = __shfl(msrc, j + half);
            const uint2 w = H64[(size_t)s * 32 + q];
            a0 += __uint_as_float(w.x << 16);
            a1 += __uint_as_float(w.x & 0xffff0000u);
            a2 += __uint_as_float(w.y << 16);
            a3 += __uint_as_float(w.y & 0xffff0000u);
        }
        if (j < nv) {                    // odd tail: half 0 only
            const int s = __shfl(msrc, j);
            if (half == 0) {
                const uint2 w = H64[(size_t)s * 32 + q];
                a0 += __uint_as_float(w.x << 16);
                a1 += __uint_as_float(w.x & 0xffff0000u);
                a2 += __uint_as_float(w.y << 16);
                a3 += __uint_as_float(w.y & 0xffff0000u);
            }
        }
    }
    // combine even/odd halves (lane l <-> l^32)
    a0 += __shfl_xor(a0, 32, 64);
    a1 += __shfl_xor(a1, 32, 64);
    a2 += __shfl_xor(a2, 32, 64);
    a3 += __shfl_xor(a3, 32, 64);
    if (half == 0) {
        const float inv = 1.0f / (float)max(end - beg, 1);
        uint2 o;
        o.x = (unsigned int)f2bf(a0 * inv) | ((unsigned int)f2bf(a1 * inv) << 16);
        o.y = (unsigned int)f2bf(a2 * inv) | ((unsigned int)f2bf(a3 * inv) << 16);
        ((uint2*)Mb)[(size_t)node * 32 + q] = o;
    }
}

// ---------------- MFMA GEMM: h' = relu([Mb | H] @ [Wl;Wr] + b) ----------------
// RESTRUCTURED (R5): 4 waves x 32 rows (2 row-tiles/wave) = 128 rows/block.
// Rationale: previously all 8 waves re-read IDENTICAL B-fragments from LDS --
// 512 ds_read_b128/CU/stage (~6100 cy) vs 3200 cy MFMA: LDS-read-pipe bound
// with MfmaUtil pinned at 13%. Two row-tiles per wave halve LDS reads per unit
// of matrix work (each B-read feeds 2 MFMAs) and give 4 independent acc chains
// per wave (2 col x 2 row) instead of 2, breaking the 20-deep serial MFMA
// dependency. W staging pipeline unchanged: FOUR 32 KB stages through a
// 2 x 32 KB double buffer via global_load_lds, raw s_barrier + COUNTED vmcnt.
// Ledger (A:24, L0..L3: 8 each, no stores until end): vmcnt(8) before
// C0/C1/C2, vmcnt(0) before C3.
// LDS = 64 KB W dbuf + 8 KB bounce (4 waves x 2 KB) = 72 KB -> 2 blocks/CU;
// VGPR ~200 -> 2 waves/SIMD: both limits agree at 8 waves/CU.
// Layer 3 computes rowdot[row] = sum_col relu(.)*Wro[col] (no h' write).
__global__ __launch_bounds__(256, 2) void gemm_kernel(const u16* __restrict__ Mb,
                                                      const u16* Hhi, const u16* Hlo,
                                                      const u16* __restrict__ Wph,
                                                      const u16* __restrict__ Wpl,
                                                      const float* __restrict__ bias,
                                                      u16* OHhi, u16* OHlo,
                                                      const float* __restrict__ Wro,
                                                      float* rowdot) {
    __shared__ uint4 ldsAll[4608];   // 72 KB: W dbuf [0:4096) + C bounce [4096:4608)
    const int t = threadIdx.x;
    const int lane = t & 63;
    const int wv = t >> 6;                       // 0..3
    const int m0 = blockIdx.x * 128 + wv * 32;   // wave owns rows [m0, m0+32)
    int rm0 = m0 + (lane & 15);        if (rm0 >= N_NODES) rm0 = 0;
    int rm1 = m0 + 16 + (lane & 15);   if (rm1 >= N_NODES) rm1 = 0;
    const int ko = (lane >> 4) * 8;

    // A fragments for both row-tiles: 24 direct 16 B loads (oldest in ledger)
    short8 am0[4], ah0[4], al0[4], am1[4], ah1[4], al1[4];
    #pragma unroll
    for (int kt = 0; kt < 4; ++kt) {
        am0[kt] = *(const short8*)(Mb  + (size_t)rm0 * D + kt * 32 + ko);
        ah0[kt] = *(const short8*)(Hhi + (size_t)rm0 * D + kt * 32 + ko);
        al0[kt] = *(const short8*)(Hlo + (size_t)rm0 * D + kt * 32 + ko);
        am1[kt] = *(const short8*)(Mb  + (size_t)rm1 * D + kt * 32 + ko);
        ah1[kt] = *(const short8*)(Hhi + (size_t)rm1 * D + kt * 32 + ko);
        al1[kt] = *(const short8*)(Hlo + (size_t)rm1 * D + kt * 32 + ko);
    }

    const int cl = lane & 15;
    const int g4 = (lane >> 4) << 2;
    char* bounceB = (char*)ldsAll + 65536 + wv * 2048;   // per-wave 2 KB

    f32x4 accA[2][4], accB[2][4];   // [si][nt2] for row-tile 0 / 1

    // stage q (32 KB: hi 16 KB + lo 16 KB) into buffer B. 8 gloads/thread.
    // dest uint4 idx = B*2048 + plane*1024 + i_*256 + wv*64 (+lane by HW)
    // matches global uint4 idx = Q*1024 + i_*256 + t.
#define STAGE_W(Q, B) do {                                                      \
        const uint4* gh_ = (const uint4*)Wph + (Q) * 1024;                      \
        const uint4* gl_ = (const uint4*)Wpl + (Q) * 1024;                      \
        _Pragma("unroll")                                                       \
        for (int i_ = 0; i_ < 4; ++i_) {                                        \
            gload16(gh_ + t + 256 * i_,                                         \
                    (void*)&ldsAll[(B) * 2048 + i_ * 256 + wv * 64]);           \
            gload16(gl_ + t + 256 * i_,                                         \
                    (void*)&ldsAll[(B) * 2048 + 1024 + i_ * 256 + wv * 64]);    \
        }                                                                       \
    } while (0)

    // compute stage Q from buffer B: 2 col-tiles x 8 kt; each B-read feeds both
    // row-tiles (5-MFMA hi/lo pattern per tile pair -> 10 MFMA per kt>=4).
#define COMPUTE_S(Q, B) do {                                                    \
        const u16* bufU_ = (const u16*)(ldsAll + (B) * 2048);                   \
        _Pragma("unroll")                                                       \
        for (int l_ = 0; l_ < 2; ++l_) {                                        \
            f32x4 a0_ = {0.f, 0.f, 0.f, 0.f};                                   \
            f32x4 a1_ = {0.f, 0.f, 0.f, 0.f};                                   \
            _Pragma("unroll")                                                   \
            for (int kt_ = 0; kt_ < 8; ++kt_) {                                 \
                const int fo_ = (l_ * 8 + kt_) * 512 + lane * 8;                \
                const short8 bh_ = *(const short8*)(bufU_ + fo_);               \
                const short8 bl_ = *(const short8*)(bufU_ + 8192 + fo_);        \
                if (kt_ < 4) {                                                  \
                    a0_ = __builtin_amdgcn_mfma_f32_16x16x32_bf16(am0[kt_], bh_, a0_, 0, 0, 0); \
                    a1_ = __builtin_amdgcn_mfma_f32_16x16x32_bf16(am1[kt_], bh_, a1_, 0, 0, 0); \
                    a0_ = __builtin_amdgcn_mfma_f32_16x16x32_bf16(am0[kt_], bl_, a0_, 0, 0, 0); \
                    a1_ = __builtin_amdgcn_mfma_f32_16x16x32_bf16(am1[kt_], bl_, a1_, 0, 0, 0); \
                } else {                                                        \
                    a0_ = __builtin_amdgcn_mfma_f32_16x16x32_bf16(ah0[kt_ - 4], bh_, a0_, 0, 0, 0); \
                    a1_ = __builtin_amdgcn_mfma_f32_16x16x32_bf16(ah1[kt_ - 4], bh_, a1_, 0, 0, 0); \
                    a0_ = __builtin_amdgcn_mfma_f32_16x16x32_bf16(ah0[kt_ - 4], bl_, a0_, 0, 0, 0); \
                    a1_ = __builtin_amdgcn_mfma_f32_16x16x32_bf16(ah1[kt_ - 4], bl_, a1_, 0, 0, 0); \
                    a0_ = __builtin_amdgcn_mfma_f32_16x16x32_bf16(al0[kt_ - 4], bh_, a0_, 0, 0, 0); \
                    a1_ = __builtin_amdgcn_mfma_f32_16x16x32_bf16(al1[kt_ - 4], bh_, a1_, 0, 0, 0); \
                }                                                               \
            }                                                                   \
            accA[(Q) >> 1][((Q) & 1) * 2 + l_] = a0_;                           \
            accB[(Q) >> 1][((Q) & 1) * 2 + l_] = a1_;                           \
        }                                                                       \
    } while (0)

    STAGE_W(0, 0);
    __builtin_amdgcn_sched_barrier(0);          // keep L0 older than L1 in ledger
    STAGE_W(1, 1);
    asm volatile("s_waitcnt vmcnt(8)" ::: "memory");   // A + L0 done, L1 in flight
    __builtin_amdgcn_s_barrier();
    COMPUTE_S(0, 0);
    __builtin_amdgcn_s_barrier();               // all waves done reading buf0
    STAGE_W(2, 0);
    asm volatile("s_waitcnt vmcnt(8)" ::: "memory");   // L1 done, L2 in flight
    __builtin_amdgcn_s_barrier();
    COMPUTE_S(1, 1);
    __builtin_amdgcn_s_barrier();               // all waves done reading buf1
    STAGE_W(3, 1);
    asm volatile("s_waitcnt vmcnt(8)" ::: "memory");   // L2 done, L3 in flight
    __builtin_amdgcn_s_barrier();
    COMPUTE_S(2, 0);
    asm volatile("s_waitcnt vmcnt(0)" ::: "memory");   // L3 done (had all of C2)
    __builtin_amdgcn_s_barrier();
    COMPUTE_S(3, 1);

    if (rowdot) {
        float ws0[4] = {0.f, 0.f, 0.f, 0.f};
        float ws1[4] = {0.f, 0.f, 0.f, 0.f};
        #pragma unroll
        for (int si = 0; si < 2; ++si) {
            #pragma unroll
            for (int nt2 = 0; nt2 < 4; ++nt2) {
                const int col = (si * 4 + nt2) * 16 + cl;
                const float bv = bias[col];
                const float wroc = Wro[col];
                #pragma unroll
                for (int r = 0; r < 4; ++r) {
                    ws0[r] = fmaf(fmaxf(accA[si][nt2][r] + bv, 0.f), wroc, ws0[r]);
                    ws1[r] = fmaf(fmaxf(accB[si][nt2][r] + bv, 0.f), wroc, ws1[r]);
                }
            }
        }
        #pragma unroll
        for (int r = 0; r < 4; ++r) {
            float t0 = ws0[r], t1 = ws1[r];
            t0 += __shfl_down(t0, 8, 64);  t1 += __shfl_down(t1, 8, 64);
            t0 += __shfl_down(t0, 4, 64);  t1 += __shfl_down(t1, 4, 64);
            t0 += __shfl_down(t0, 2, 64);  t1 += __shfl_down(t1, 2, 64);
            t0 += __shfl_down(t0, 1, 64);  t1 += __shfl_down(t1, 1, 64);
            if (cl == 0) {
                const int row0 = m0 + g4 + r;
                const int row1 = m0 + 16 + g4 + r;
                if (row0 < N_NODES) rowdot[row0] = t0;
                if (row1 < N_NODES) rowdot[row1] = t1;
            }
        }
    } else {
        #pragma unroll
        for (int si = 0; si < 2; ++si) {
            #pragma unroll
            for (int p = 0; p < 2; ++p) {
                // pass 1: bias+relu+split; hi plane -> swizzled LDS, lo bits -> regs
                asm volatile("s_waitcnt lgkmcnt(0)" ::: "memory");  // prior readback done
                unsigned int lo_pack[8];
                #pragma unroll
                for (int nt2 = 0; nt2 < 4; ++nt2) {
                    const int col = (si * 4 + nt2) * 16 + cl;
                    const float bv = bias[col];
                    #pragma unroll
                    for (int r = 0; r < 4; ++r) {
                        const int row16 = g4 + r;
                        const f32x4 av = p ? accB[si][nt2] : accA[si][nt2];
                        const float v = fmaxf(av[r] + bv, 0.f);
                        unsigned int h16, l16;
                        split2(v, h16, l16);
                        const int boff = (row16 * 128 + (nt2 * 16 + cl) * 2) ^ ((row16 & 7) << 4);
                        *(u16*)(bounceB + boff) = (u16)h16;
                        if (r & 1) lo_pack[nt2 * 2 + (r >> 1)] |= l16 << 16;
                        else       lo_pack[nt2 * 2 + (r >> 1)]  = l16;
                    }
                }
                asm volatile("s_waitcnt lgkmcnt(0)" ::: "memory");
                // hi readback: contiguous 16 B/lane, full 128 B row chunks
                #pragma unroll
                for (int j = 0; j < 2; ++j) {
                    const int row16 = j * 8 + (lane >> 3);
                    const int blk = lane & 7;
                    const uint4 vv = *(const uint4*)(bounceB + row16 * 128 + ((blk ^ (row16 & 7)) << 4));
                    const int grow = m0 + p * 16 + row16;
                    if (grow < N_NODES)
                        *(uint4*)(OHhi + (size_t)grow * D + si * 64 + blk * 8) = vv;
                }
                asm volatile("s_waitcnt lgkmcnt(0)" ::: "memory");
                // pass 2: lo plane through the same bounce tile
                #pragma unroll
                for (int nt2 = 0; nt2 < 4; ++nt2) {
                    #pragma unroll
                    for (int r = 0; r < 4; ++r) {
                        const int row16 = g4 + r;
                        const unsigned int l16 = (lo_pack[nt2 * 2 + (r >> 1)] >> ((r & 1) * 16)) & 0xffffu;
                        const int boff = (row16 * 128 + (nt2 * 16 + cl) * 2) ^ ((row16 & 7) << 4);
                        *(u16*)(bounceB + boff) = (u16)l16;
                    }
                }
                asm volatile("s_waitcnt lgkmcnt(0)" ::: "memory");
                #pragma unroll
                for (int j = 0; j < 2; ++j) {
                    const int row16 = j * 8 + (lane >> 3);
                    const int blk = lane & 7;
                    const uint4 vv = *(const uint4*)(bounceB + row16 * 128 + ((blk ^ (row16 & 7)) << 4));
                    const int grow = m0 + p * 16 + row16;
                    if (grow < N_NODES)
                        *(uint4*)(OHlo + (size_t)grow * D + si * 64 + blk * 8) = vv;
                }
            }
        }
    }
#undef STAGE_W
#undef COMPUTE_S
}

// ---------------- final: per-graph sum of rowdot + sigmoid (batch sorted) ----------------
__global__ __launch_bounds__(64) void final_kernel(const float* __restrict__ rowdot,
                                                   const int* __restrict__ batch,
                                                   const float* __restrict__ bro,
                                                   float* __restrict__ out) {
    const int g = blockIdx.x;
    const int t = threadIdx.x;
    int lo = 0, hi = N_NODES;
    while (lo < hi) { int mid = (lo + hi) >> 1; if (batch[mid] < g) lo = mid + 1; else hi = mid; }
    int lo2 = lo, hi2 = N_NODES;
    while (lo2 < hi2) { int mid = (lo2 + hi2) >> 1; if (batch[mid] < g + 1) lo2 = mid + 1; else hi2 = mid; }

    float acc = 0.0f;
    for (int i = lo + t; i < lo2; i += 64) acc += rowdot[i];
    #pragma unroll
    for (int off = 32; off > 0; off >>= 1) acc += __shfl_down(acc, off, 64);
    if (t == 0) out[g] = 1.0f / (1.0f + expf(-(acc + bro[0])));
}

extern "C" void kernel_launch(void* const* d_in, const int* in_sizes, int n_in,
                              void* d_out, int out_size, void* d_ws, size_t ws_size,
                              hipStream_t stream) {
    const float* x     = (const float*)d_in[0];
    const int*   ei    = (const int*)d_in[1];
    const int*   batch = (const int*)d_in[2];
    const int*   src   = ei;
    const int*   dst   = ei + N_EDGES;
    const float* Wl[3] = {(const float*)d_in[3], (const float*)d_in[6], (const float*)d_in[9]};
    const float* Wr[3] = {(const float*)d_in[4], (const float*)d_in[7], (const float*)d_in[10]};
    const float* bs[3] = {(const float*)d_in[5], (const float*)d_in[8], (const float*)d_in[11]};
    const float* Wro   = (const float*)d_in[12];
    const float* bro   = (const float*)d_in[13];
    float* out = (float*)d_out;

    const size_t ND = (size_t)N_NODES * D;
    char* ws = (char*)d_ws;
    u16* Hhi = (u16*)ws;                           // ND u16
    u16* Hlo = Hhi + ND;                           // ND u16
    u16* Mb  = Hlo + ND;                           // ND u16 (bf16 mean)
    u16* Wph = Mb + ND;                            // 3*32768 u16
    u16* Wpl = Wph + 3 * 32768;                    // 3*32768 u16
    int* deg      = (int*)(Wpl + 3 * 32768);       // N (deg+fill zeroed together)
    int* fill     = deg + N_NODES;                 // N
    float* rowdot = (float*)(fill + N_NODES);      // N
    int* excl     = (int*)(rowdot + N_NODES);      // N
    int* blocksum = excl + N_NODES;                // 128
    int* rowptr   = blocksum + 128;                // N+1
    int* csr_src  = rowptr + N_NODES + 1;          // E

    const int EB      = (N_EDGES + 255) / 256;
    const int NB      = (N_NODES + 255) / 256;
    const int NB2     = (2 * N_NODES + 255) / 256;
    const int EPB     = ((E4 + 255) / 256) * NPART;          // partitioned (fill)
    const int PREP_B  = SPLIT_B + 48;                        // fused split + wprep
    const int AGG_B   = N_NODES / 4;                         // 25000
    const int GEMM_B  = (N_NODES + 127) / 128;               // 782

    // ---- CSR build ----
    zero_i_kernel<<<NB2, 256, 0, stream>>>(deg, 2 * N_NODES);
    hist_kernel<<<EB, 256, 0, stream>>>(dst, deg);
    scan1_kernel<<<SCAN_NBC, SCAN_BS, 0, stream>>>(deg, excl, blocksum);
    scan3_kernel<<<NB, 256, 0, stream>>>(excl, blocksum, rowptr);
    fill_kernel<<<EPB, 256, 0, stream>>>(src, dst, rowptr, fill, csr_src);

    // ---- fused prep: split x + pack weights ----
    prep_kernel<<<PREP_B, 256, 0, stream>>>(x, Hhi, Hlo,
                                            Wl[0], Wr[0], Wl[1], Wr[1], Wl[2], Wr[2],
                                            Wph, Wpl);

    // ---- 3 layers: aggregate (hi-plane gather) then GEMM; layer 3 -> rowdot ----
    for (int l = 0; l < 3; ++l) {
        float* rdl = (l == 2) ? rowdot : (float*)nullptr;
        agg_kernel<<<AGG_B, 256, 0, stream>>>(Hhi, rowptr, csr_src, Mb);
        gemm_kernel<<<GEMM_B, 256, 0, stream>>>(Mb, Hhi, Hlo,
                                                Wph + l * 32768, Wpl + l * 32768, bs[l],
                                                Hhi, Hlo, Wro, rdl);
    }

    // ---- per-graph sum + sigmoid ----
    final_kernel<<<N_GRAPHS, 64, 0, stream>>>(rowdot, batch, bro, out);
}

// Round 6
// 361.991 us; speedup vs baseline: 1.0841x; 1.0841x over previous
//
#include <hip/hip_runtime.h>
#include <math.h>

#define N_NODES 100000
#define N_EDGES 600000
#define N_GRAPHS 512
#define D 128
#define SCAN_BS 1024
#define SCAN_NBC ((N_NODES + SCAN_BS - 1) / SCAN_BS)   // 98
#define NPART 8
#define PART_SZ (N_NODES / NPART)                      // 12500
#define E4 (N_EDGES / 4)                               // 150000
#define SPLIT_B 12500                                  // (N*D/4)/256

typedef unsigned short u16;
typedef __attribute__((ext_vector_type(8))) short short8;
typedef __attribute__((ext_vector_type(4))) float f32x4;

__device__ __forceinline__ u16 f2bf(float f) {
    unsigned int u = __float_as_uint(f);
    u += 0x7FFFu + ((u >> 16) & 1u);
    return (u16)(u >> 16);
}
__device__ __forceinline__ float bf2f(u16 h) {
    return __uint_as_float(((unsigned int)h) << 16);
}
// fp32 -> (hi bf16 bits, lo bf16 bits) in low 16 of each
__device__ __forceinline__ void split2(float f, unsigned int& h16, unsigned int& l16) {
    unsigned int u = __float_as_uint(f);
    unsigned int hb = (u + (0x7FFFu + ((u >> 16) & 1u))) & 0xffff0000u;
    float lo = f - __uint_as_float(hb);
    unsigned int ul = __float_as_uint(lo);
    h16 = hb >> 16;
    l16 = (ul + (0x7FFFu + ((ul >> 16) & 1u))) >> 16;
}

// async global->LDS, 16 B per lane. LDS dest must be wave-uniform base + lane*16.
typedef __attribute__((address_space(1))) const unsigned int gas_u32;
typedef __attribute__((address_space(3))) unsigned int las_u32;
__device__ __forceinline__ void gload16(const void* g, void* l) {
    __builtin_amdgcn_global_load_lds((gas_u32*)g, (las_u32*)l, 16, 0, 0);
}

// ---------------- zero helper ----------------
__global__ __launch_bounds__(256) void zero_i_kernel(int* __restrict__ p, int n) {
    int i = blockIdx.x * 256 + threadIdx.x;
    if (i < n) p[i] = 0;
}

// ---------------- CSR build ----------------
// hist: plain unpartitioned (atomics execute at the device coherence point --
// R3 post-mortem). fill: KEEPS dst-range partitioning: its win is the csr_src
// SCATTER-STORE locality in the owning XCD's L2 (R2->R3).
__global__ __launch_bounds__(256) void hist_kernel(const int* __restrict__ dst,
                                                   int* __restrict__ deg) {
    int e = blockIdx.x * 256 + threadIdx.x;
    if (e < N_EDGES) atomicAdd(&deg[dst[e]], 1);
}

__global__ __launch_bounds__(1024) void scan1_kernel(const int* __restrict__ deg,
                                                     int* __restrict__ excl,
                                                     int* __restrict__ blocksum) {
    __shared__ int buf[2][SCAN_BS];
    const int t = threadIdx.x;
    const int gid = blockIdx.x * SCAN_BS + t;
    int v = (gid < N_NODES) ? deg[gid] : 0;
    buf[0][t] = v;
    __syncthreads();
    int pi = 0;
    for (int off = 1; off < SCAN_BS; off <<= 1) {
        int val = buf[pi][t];
        if (t >= off) val += buf[pi][t - off];
        buf[pi ^ 1][t] = val;
        pi ^= 1;
        __syncthreads();
    }
    int incl = buf[pi][t];
    if (gid < N_NODES) excl[gid] = incl - v;
    if (t == SCAN_BS - 1) blocksum[blockIdx.x] = incl;
}

// scan3 with the block-total prefix computed locally (merged scan2)
__global__ __launch_bounds__(256) void scan3_kernel(const int* __restrict__ excl,
                                                    const int* __restrict__ blocksum,
                                                    int* __restrict__ rowptr) {
    __shared__ int buf[2][128];
    const int t = threadIdx.x;
    if (t < 128) buf[0][t] = (t < SCAN_NBC) ? blocksum[t] : 0;
    __syncthreads();
    int pi = 0;
    for (int off = 1; off < 128; off <<= 1) {
        if (t < 128) {
            int val = buf[pi][t];
            if (t >= off) val += buf[pi][t - off];
            buf[pi ^ 1][t] = val;
        }
        pi ^= 1;
        __syncthreads();
    }
    const int i = blockIdx.x * 256 + t;
    if (i < N_NODES) {
        const int j = i / SCAN_BS;
        const int pref = (j == 0) ? 0 : buf[pi][j - 1];
        rowptr[i] = excl[i] + pref;
    }
    if (i == 0) rowptr[N_NODES] = N_EDGES;
}

__global__ __launch_bounds__(256) void fill_kernel(const int* __restrict__ src,
                                                   const int* __restrict__ dst,
                                                   const int* __restrict__ rowptr,
                                                   int* __restrict__ fill,
                                                   int* __restrict__ csr_src) {
    const int lo = (blockIdx.x & (NPART - 1)) * PART_SZ;
    const int i4 = (blockIdx.x >> 3) * 256 + threadIdx.x;
    if (i4 >= E4) return;
    const int4 d4 = ((const int4*)dst)[i4];
    const int4 s4 = ((const int4*)src)[i4];
    if ((unsigned)(d4.x - lo) < (unsigned)PART_SZ) {
        int pos = rowptr[d4.x] + atomicAdd(&fill[d4.x], 1);
        csr_src[pos] = s4.x;
    }
    if ((unsigned)(d4.y - lo) < (unsigned)PART_SZ) {
        int pos = rowptr[d4.y] + atomicAdd(&fill[d4.y], 1);
        csr_src[pos] = s4.y;
    }
    if ((unsigned)(d4.z - lo) < (unsigned)PART_SZ) {
        int pos = rowptr[d4.z] + atomicAdd(&fill[d4.z], 1);
        csr_src[pos] = s4.z;
    }
    if ((unsigned)(d4.w - lo) < (unsigned)PART_SZ) {
        int pos = rowptr[d4.w] + atomicAdd(&fill[d4.w], 1);
        csr_src[pos] = s4.w;
    }
}

// ---------------- fused prep: split x into bf16 hi/lo planes + pack W ----------------
__global__ __launch_bounds__(256) void prep_kernel(const float* __restrict__ x,
                                                   u16* __restrict__ Hhi,
                                                   u16* __restrict__ Hlo,
                                                   const float* __restrict__ Wl1, const float* __restrict__ Wr1,
                                                   const float* __restrict__ Wl2, const float* __restrict__ Wr2,
                                                   const float* __restrict__ Wl3, const float* __restrict__ Wr3,
                                                   u16* __restrict__ wph, u16* __restrict__ wpl) {
    if (blockIdx.x < SPLIT_B) {
        const int i = blockIdx.x * 256 + threadIdx.x;   // 4 elems/thread
        const float4 v = ((const float4*)x)[i];
        unsigned int h0, l0, h1, l1, h2, l2, h3, l3;
        split2(v.x, h0, l0); split2(v.y, h1, l1);
        split2(v.z, h2, l2); split2(v.w, h3, l3);
        uint2 oh, ol;
        oh.x = h0 | (h1 << 16); oh.y = h2 | (h3 << 16);
        ol.x = l0 | (l1 << 16); ol.y = l2 | (l3 << 16);
        ((uint2*)Hhi)[i] = oh;
        ((uint2*)Hlo)[i] = ol;
    } else {
        const int b = (blockIdx.x - SPLIT_B) * 4 + (threadIdx.x >> 6);  // 0..191
        const int lane = threadIdx.x & 63;
        const int layer = b >> 6;
        const int t = b & 63;
        const float* Wl = (layer == 0) ? Wl1 : (layer == 1) ? Wl2 : Wl3;
        const float* Wr = (layer == 0) ? Wr1 : (layer == 1) ? Wr2 : Wr3;
        const int nt = t >> 3, kt = t & 7;
        const int n = nt * 16 + (lane & 15);
        const int k0 = kt * 32 + (lane >> 4) * 8;
        const size_t base = (size_t)layer * 32768 + (size_t)(t * 64 + lane) * 8;
        #pragma unroll
        for (int j = 0; j < 8; ++j) {
            const int k = k0 + j;
            const float w = (k < 128) ? Wl[k * 128 + n] : Wr[(k - 128) * 128 + n];
            const u16 h = f2bf(w);
            wph[base + j] = h;
            wpl[base + j] = f2bf(w - bf2f(h));
        }
    }
}

// ---------------- FUSED agg + MFMA GEMM ----------------
// h' = relu([mean_nbr(INhi) | IN] @ [Wl;Wr] + b), OUT != IN (ping-pong), so the
// neighbor gather (reads arbitrary rows of INhi) cannot race the epilogue
// writes. This removes the separate agg kernel and the 25.6 MB Mb buffer
// (51 MB/layer of HBM round-trip) and hides gather latency under co-resident
// blocks' MFMA/staging (16 waves/CU).
// Structure: 8 waves x 16 rows = 128 rows/block (R1 skeleton, best measured).
// Prologue per lane: aggregate its 32 A-fragment columns (4 lanes/row jointly
// cover the full 256 B neighbor row as aligned 64 B segments) in fp32, round
// with f2bf -- bit-identical to the old agg->Mb->load path (fp32 sums of bf16
// are exact here; 3 prior sum reorders all kept absmax 0).
// W pipeline unchanged from R1: four 32 KB stages, 2x32 KB LDS dbuf via
// global_load_lds, raw s_barrier + counted vmcnt. Ledger (gather fully drained
// by its own data-dep waits + sched_barrier; then A:8, L:4/stage): vmcnt(4)
// before C0/C1/C2, vmcnt(0) before C3. LDS 80 KB -> 2 blocks/CU.
// Layer 3: rowdot[row] = sum_col relu(.)*Wro[col] (no h' write).
__global__ __launch_bounds__(512, 4) void gemm_kernel(const u16* __restrict__ INhi,
                                                      const u16* __restrict__ INlo,
                                                      const int* __restrict__ rowptr,
                                                      const int* __restrict__ csr_src,
                                                      const u16* __restrict__ Wph,
                                                      const u16* __restrict__ Wpl,
                                                      const float* __restrict__ bias,
                                                      u16* __restrict__ OHhi,
                                                      u16* __restrict__ OHlo,
                                                      const float* __restrict__ Wro,
                                                      float* rowdot) {
    __shared__ uint4 ldsAll[5120];   // 80 KB: W dbuf [0:4096) + C bounce [4096:5120)
    const int t = threadIdx.x;
    const int lane = t & 63;
    const int wv = t >> 6;
    const int m0 = blockIdx.x * 128 + wv * 16;
    const int row16 = m0 + (lane & 15);
    int rm = row16; if (rm >= N_NODES) rm = 0;
    const int ko = (lane >> 4) * 8;

    // ---- fused aggregation: mean of neighbor rows, this lane's 32 cols ----
    int beg = 0, deg = 0;
    if (row16 < N_NODES) {
        beg = rowptr[row16];
        deg = rowptr[row16 + 1] - beg;
    }
    float ac[4][8];
    #pragma unroll
    for (int kt = 0; kt < 4; ++kt) {
        #pragma unroll
        for (int j = 0; j < 8; ++j) ac[kt][j] = 0.f;
    }
    int s_cur = (deg > 0) ? csr_src[beg] : 0;
    for (int n = 0; __any(n < deg); ++n) {
        const bool act = n < deg;
        const int s_nxt = (n + 1 < deg) ? csr_src[beg + n + 1] : 0;
        if (act) {
            const size_t rb = (size_t)s_cur * D + ko;
            #pragma unroll
            for (int kt = 0; kt < 4; ++kt) {
                const uint4 v = *(const uint4*)(INhi + rb + kt * 32);
                ac[kt][0] += __uint_as_float(v.x << 16);
                ac[kt][1] += __uint_as_float(v.x & 0xffff0000u);
                ac[kt][2] += __uint_as_float(v.y << 16);
                ac[kt][3] += __uint_as_float(v.y & 0xffff0000u);
                ac[kt][4] += __uint_as_float(v.z << 16);
                ac[kt][5] += __uint_as_float(v.z & 0xffff0000u);
                ac[kt][6] += __uint_as_float(v.w << 16);
                ac[kt][7] += __uint_as_float(v.w & 0xffff0000u);
            }
        }
        s_cur = s_nxt;
    }
    const float inv = 1.0f / (float)max(deg, 1);
    short8 am[4];
    #pragma unroll
    for (int kt = 0; kt < 4; ++kt) {
        uint4 u;
        u.x = (unsigned)f2bf(ac[kt][0] * inv) | ((unsigned)f2bf(ac[kt][1] * inv) << 16);
        u.y = (unsigned)f2bf(ac[kt][2] * inv) | ((unsigned)f2bf(ac[kt][3] * inv) << 16);
        u.z = (unsigned)f2bf(ac[kt][4] * inv) | ((unsigned)f2bf(ac[kt][5] * inv) << 16);
        u.w = (unsigned)f2bf(ac[kt][6] * inv) | ((unsigned)f2bf(ac[kt][7] * inv) << 16);
        am[kt] = __builtin_bit_cast(short8, u);
    }
    __builtin_amdgcn_sched_barrier(0);   // fence gather VMEM out of the ledger

    // root A fragments: 8 direct 16 B loads (oldest in ledger)
    short8 ah[4], al[4];
    #pragma unroll
    for (int kt = 0; kt < 4; ++kt) {
        ah[kt] = *(const short8*)(INhi + (size_t)rm * D + kt * 32 + ko);
        al[kt] = *(const short8*)(INlo + (size_t)rm * D + kt * 32 + ko);
    }

    const int cl = lane & 15;
    const int g4 = (lane >> 4) << 2;
    char* bounceB = (char*)ldsAll + 65536 + wv * 2048;   // per-wave 2 KB

    f32x4 acc8[2][4];   // [s][nt2], all indices compile-time after unroll

#define STAGE_W(Q, B) do {                                                      \
        const uint4* gh_ = (const uint4*)Wph + (Q) * 1024;                      \
        const uint4* gl_ = (const uint4*)Wpl + (Q) * 1024;                      \
        _Pragma("unroll")                                                       \
        for (int i_ = 0; i_ < 2; ++i_) {                                        \
            gload16(gh_ + t + 512 * i_,                                         \
                    (void*)&ldsAll[(B) * 2048 + wv * 64 + 512 * i_]);           \
            gload16(gl_ + t + 512 * i_,                                         \
                    (void*)&ldsAll[(B) * 2048 + 1024 + wv * 64 + 512 * i_]);    \
        }                                                                       \
    } while (0)

#define COMPUTE_S(Q, B) do {                                                    \
        const u16* bufU_ = (const u16*)(ldsAll + (B) * 2048);                   \
        _Pragma("unroll")                                                       \
        for (int l_ = 0; l_ < 2; ++l_) {                                        \
            f32x4 acc_ = {0.f, 0.f, 0.f, 0.f};                                  \
            _Pragma("unroll")                                                   \
            for (int kt_ = 0; kt_ < 8; ++kt_) {                                 \
                const int fo_ = (l_ * 8 + kt_) * 512 + lane * 8;                \
                const short8 bh_ = *(const short8*)(bufU_ + fo_);               \
                const short8 bl_ = *(const short8*)(bufU_ + 8192 + fo_);        \
                if (kt_ < 4) {                                                  \
                    acc_ = __builtin_amdgcn_mfma_f32_16x16x32_bf16(am[kt_], bh_, acc_, 0, 0, 0); \
                    acc_ = __builtin_amdgcn_mfma_f32_16x16x32_bf16(am[kt_], bl_, acc_, 0, 0, 0); \
                } else {                                                        \
                    acc_ = __builtin_amdgcn_mfma_f32_16x16x32_bf16(ah[kt_ - 4], bh_, acc_, 0, 0, 0); \
                    acc_ = __builtin_amdgcn_mfma_f32_16x16x32_bf16(ah[kt_ - 4], bl_, acc_, 0, 0, 0); \
                    acc_ = __builtin_amdgcn_mfma_f32_16x16x32_bf16(al[kt_ - 4], bh_, acc_, 0, 0, 0); \
                }                                                               \
            }                                                                   \
            acc8[(Q) >> 1][((Q) & 1) * 2 + l_] = acc_;                          \
        }                                                                       \
    } while (0)

    STAGE_W(0, 0);
    __builtin_amdgcn_sched_barrier(0);          // keep L0 older than L1 in ledger
    STAGE_W(1, 1);
    asm volatile("s_waitcnt vmcnt(4)" ::: "memory");   // A + L0 done, L1 in flight
    __builtin_amdgcn_s_barrier();
    COMPUTE_S(0, 0);
    __builtin_amdgcn_s_barrier();               // all waves done reading buf0
    STAGE_W(2, 0);
    asm volatile("s_waitcnt vmcnt(4)" ::: "memory");   // L1 done, L2 in flight
    __builtin_amdgcn_s_barrier();
    COMPUTE_S(1, 1);
    __builtin_amdgcn_s_barrier();               // all waves done reading buf1
    STAGE_W(3, 1);
    asm volatile("s_waitcnt vmcnt(4)" ::: "memory");   // L2 done, L3 in flight
    __builtin_amdgcn_s_barrier();
    COMPUTE_S(2, 0);
    asm volatile("s_waitcnt vmcnt(0)" ::: "memory");   // L3 done (had all of C2)
    __builtin_amdgcn_s_barrier();
    COMPUTE_S(3, 1);

    if (rowdot) {
        float wsum[4] = {0.f, 0.f, 0.f, 0.f};
        #pragma unroll
        for (int si = 0; si < 2; ++si) {
            #pragma unroll
            for (int nt2 = 0; nt2 < 4; ++nt2) {
                const int col = (si * 4 + nt2) * 16 + cl;
                const float bv = bias[col];
                const float wroc = Wro[col];
                #pragma unroll
                for (int r = 0; r < 4; ++r) {
                    const float v = fmaxf(acc8[si][nt2][r] + bv, 0.f);
                    wsum[r] = fmaf(v, wroc, wsum[r]);
                }
            }
        }
        #pragma unroll
        for (int r = 0; r < 4; ++r) {
            float tsum = wsum[r];
            tsum += __shfl_down(tsum, 8, 64);
            tsum += __shfl_down(tsum, 4, 64);
            tsum += __shfl_down(tsum, 2, 64);
            tsum += __shfl_down(tsum, 1, 64);
            const int row = m0 + g4 + r;
            if (cl == 0 && row < N_NODES) {
                rowdot[row] = tsum;   // plain store, row owned by this wave
            }
        }
    } else {
        #pragma unroll
        for (int si = 0; si < 2; ++si) {
            // pass 1: bias+relu+split; hi plane -> swizzled LDS, lo bits -> regs
            asm volatile("s_waitcnt lgkmcnt(0)" ::: "memory");  // prior readback done
            unsigned int lo_pack[8];
            #pragma unroll
            for (int nt2 = 0; nt2 < 4; ++nt2) {
                const int col = (si * 4 + nt2) * 16 + cl;
                const float bv = bias[col];
                #pragma unroll
                for (int r = 0; r < 4; ++r) {
                    const int rr = g4 + r;
                    const float v = fmaxf(acc8[si][nt2][r] + bv, 0.f);
                    unsigned int h16, l16;
                    split2(v, h16, l16);
                    const int boff = (rr * 128 + (nt2 * 16 + cl) * 2) ^ ((rr & 7) << 4);
                    *(u16*)(bounceB + boff) = (u16)h16;
                    if (r & 1) lo_pack[nt2 * 2 + (r >> 1)] |= l16 << 16;
                    else       lo_pack[nt2 * 2 + (r >> 1)]  = l16;
                }
            }
            asm volatile("s_waitcnt lgkmcnt(0)" ::: "memory");
            // hi readback: contiguous 16 B/lane, full 128 B row chunks to global
            #pragma unroll
            for (int j = 0; j < 2; ++j) {
                const int rr = j * 8 + (lane >> 3);
                const int blk = lane & 7;
                const uint4 vv = *(const uint4*)(bounceB + rr * 128 + ((blk ^ (rr & 7)) << 4));
                const int grow = m0 + rr;
                if (grow < N_NODES)
                    *(uint4*)(OHhi + (size_t)grow * D + si * 64 + blk * 8) = vv;
            }
            asm volatile("s_waitcnt lgkmcnt(0)" ::: "memory");
            // pass 2: lo plane through the same bounce tile
            #pragma unroll
            for (int nt2 = 0; nt2 < 4; ++nt2) {
                #pragma unroll
                for (int r = 0; r < 4; ++r) {
                    const int rr = g4 + r;
                    const unsigned int l16 = (lo_pack[nt2 * 2 + (r >> 1)] >> ((r & 1) * 16)) & 0xffffu;
                    const int boff = (rr * 128 + (nt2 * 16 + cl) * 2) ^ ((rr & 7) << 4);
                    *(u16*)(bounceB + boff) = (u16)l16;
                }
            }
            asm volatile("s_waitcnt lgkmcnt(0)" ::: "memory");
            #pragma unroll
            for (int j = 0; j < 2; ++j) {
                const int rr = j * 8 + (lane >> 3);
                const int blk = lane & 7;
                const uint4 vv = *(const uint4*)(bounceB + rr * 128 + ((blk ^ (rr & 7)) << 4));
                const int grow = m0 + rr;
                if (grow < N_NODES)
                    *(uint4*)(OHlo + (size_t)grow * D + si * 64 + blk * 8) = vv;
            }
        }
    }
#undef STAGE_W
#undef COMPUTE_S
}

// ---------------- final: per-graph sum of rowdot + sigmoid (batch sorted) ----------------
__global__ __launch_bounds__(64) void final_kernel(const float* __restrict__ rowdot,
                                                   const int* __restrict__ batch,
                                                   const float* __restrict__ bro,
                                                   float* __restrict__ out) {
    const int g = blockIdx.x;
    const int t = threadIdx.x;
    int lo = 0, hi = N_NODES;
    while (lo < hi) { int mid = (lo + hi) >> 1; if (batch[mid] < g) lo = mid + 1; else hi = mid; }
    int lo2 = lo, hi2 = N_NODES;
    while (lo2 < hi2) { int mid = (lo2 + hi2) >> 1; if (batch[mid] < g + 1) lo2 = mid + 1; else hi2 = mid; }

    float acc = 0.0f;
    for (int i = lo + t; i < lo2; i += 64) acc += rowdot[i];
    #pragma unroll
    for (int off = 32; off > 0; off >>= 1) acc += __shfl_down(acc, off, 64);
    if (t == 0) out[g] = 1.0f / (1.0f + expf(-(acc + bro[0])));
}

extern "C" void kernel_launch(void* const* d_in, const int* in_sizes, int n_in,
                              void* d_out, int out_size, void* d_ws, size_t ws_size,
                              hipStream_t stream) {
    const float* x     = (const float*)d_in[0];
    const int*   ei    = (const int*)d_in[1];
    const int*   batch = (const int*)d_in[2];
    const int*   src   = ei;
    const int*   dst   = ei + N_EDGES;
    const float* Wl[3] = {(const float*)d_in[3], (const float*)d_in[6], (const float*)d_in[9]};
    const float* Wr[3] = {(const float*)d_in[4], (const float*)d_in[7], (const float*)d_in[10]};
    const float* bs[3] = {(const float*)d_in[5], (const float*)d_in[8], (const float*)d_in[11]};
    const float* Wro   = (const float*)d_in[12];
    const float* bro   = (const float*)d_in[13];
    float* out = (float*)d_out;

    const size_t ND = (size_t)N_NODES * D;
    char* ws = (char*)d_ws;
    u16* Ahi = (u16*)ws;                           // ND u16 (ping-pong plane A)
    u16* Alo = Ahi + ND;                           // ND u16
    u16* Bhi = Alo + ND;                           // ND u16 (ping-pong plane B)
    u16* Blo = Bhi + ND;                           // ND u16
    u16* Wph = Blo + ND;                           // 3*32768 u16
    u16* Wpl = Wph + 3 * 32768;                    // 3*32768 u16
    int* deg      = (int*)(Wpl + 3 * 32768);       // N (deg+fill zeroed together)
    int* fill     = deg + N_NODES;                 // N
    float* rowdot = (float*)(fill + N_NODES);      // N
    int* excl     = (int*)(rowdot + N_NODES);      // N
    int* blocksum = excl + N_NODES;                // 128
    int* rowptr   = blocksum + 128;                // N+1
    int* csr_src  = rowptr + N_NODES + 1;          // E

    const int EB      = (N_EDGES + 255) / 256;
    const int NB      = (N_NODES + 255) / 256;
    const int NB2     = (2 * N_NODES + 255) / 256;
    const int EPB     = ((E4 + 255) / 256) * NPART;          // partitioned (fill)
    const int PREP_B  = SPLIT_B + 48;                        // fused split + wprep
    const int GEMM_B  = (N_NODES + 127) / 128;               // 782

    // ---- CSR build ----
    zero_i_kernel<<<NB2, 256, 0, stream>>>(deg, 2 * N_NODES);
    hist_kernel<<<EB, 256, 0, stream>>>(dst, deg);
    scan1_kernel<<<SCAN_NBC, SCAN_BS, 0, stream>>>(deg, excl, blocksum);
    scan3_kernel<<<NB, 256, 0, stream>>>(excl, blocksum, rowptr);
    fill_kernel<<<EPB, 256, 0, stream>>>(src, dst, rowptr, fill, csr_src);

    // ---- fused prep: split x + pack weights (into plane A) ----
    prep_kernel<<<PREP_B, 256, 0, stream>>>(x, Ahi, Alo,
                                            Wl[0], Wr[0], Wl[1], Wr[1], Wl[2], Wr[2],
                                            Wph, Wpl);

    // ---- 3 fused agg+GEMM layers, ping-pong A<->B; layer 3 -> rowdot ----
    // l=0: A -> B; l=1: B -> A; l=2: A -> rowdot
    gemm_kernel<<<GEMM_B, 512, 0, stream>>>(Ahi, Alo, rowptr, csr_src,
                                            Wph, Wpl, bs[0],
                                            Bhi, Blo, Wro, (float*)nullptr);
    gemm_kernel<<<GEMM_B, 512, 0, stream>>>(Bhi, Blo, rowptr, csr_src,
                                            Wph + 32768, Wpl + 32768, bs[1],
                                            Ahi, Alo, Wro, (float*)nullptr);
    gemm_kernel<<<GEMM_B, 512, 0, stream>>>(Ahi, Alo, rowptr, csr_src,
                                            Wph + 2 * 32768, Wpl + 2 * 32768, bs[2],
                                            Bhi, Blo, Wro, rowdot);

    // ---- per-graph sum + sigmoid ----
    final_kernel<<<N_GRAPHS, 64, 0, stream>>>(rowdot, batch, bro, out);
}